// Round 1
// baseline (1088.682 us; speedup 1.0000x reference)
//
#include <hip/hip_runtime.h>

// MoE block: router(top-2 of 8) -> per-expert [M,1024]@[1024,4096] GELU
// -> [M,4096]@[4096,1024] -> scale/combine -> residual + LayerNorm.
// bf16 MFMA (16x16x32), fp32 router/accum/epilogue.

#define T_TOKENS 8192
#define DM 1024
#define DF 4096
#define NE 8

typedef unsigned short u16;
typedef short v8s __attribute__((ext_vector_type(8)));
typedef float v4f __attribute__((ext_vector_type(4)));

__device__ __forceinline__ u16 f2bf(float f) {
  unsigned u = __float_as_uint(f);
  u += 0x7FFFu + ((u >> 16) & 1u);
  return (u16)(u >> 16);
}

// ---------------- x -> bf16 ----------------
__global__ __launch_bounds__(256) void cvt_x_kernel(const float* __restrict__ x,
                                                    u16* __restrict__ xb) {
  size_t i = ((size_t)blockIdx.x * 256 + threadIdx.x) * 8;
  float4 v0 = *(const float4*)(x + i);
  float4 v1 = *(const float4*)(x + i + 4);
  int4 o;
  o.x = (int)f2bf(v0.x) | ((int)f2bf(v0.y) << 16);
  o.y = (int)f2bf(v0.z) | ((int)f2bf(v0.w) << 16);
  o.z = (int)f2bf(v1.x) | ((int)f2bf(v1.y) << 16);
  o.w = (int)f2bf(v1.z) | ((int)f2bf(v1.w) << 16);
  *(int4*)(xb + i) = o;
}

// ---------------- router ----------------
__global__ __launch_bounds__(64) void router_kernel(
    const float* __restrict__ x, const float* __restrict__ rw,
    const float* __restrict__ rb, int* __restrict__ counts,
    int* __restrict__ list_token, int* __restrict__ epos,
    float* __restrict__ escore) {
  int t = blockIdx.x;
  int lane = threadIdx.x;
  const float* xr = x + (size_t)t * DM;
  float a[8] = {0.f, 0.f, 0.f, 0.f, 0.f, 0.f, 0.f, 0.f};
  for (int j = lane; j < DM; j += 64) {
    float xv = xr[j];
    const float4* r4 = (const float4*)(rw + (size_t)j * 8);
    float4 w0 = r4[0], w1 = r4[1];
    a[0] += xv * w0.x; a[1] += xv * w0.y; a[2] += xv * w0.z; a[3] += xv * w0.w;
    a[4] += xv * w1.x; a[5] += xv * w1.y; a[6] += xv * w1.z; a[7] += xv * w1.w;
  }
#pragma unroll
  for (int e = 0; e < 8; e++)
#pragma unroll
    for (int off = 32; off > 0; off >>= 1) a[e] += __shfl_down(a[e], off);
  if (lane == 0) {
    float l[8];
    float mx = -1e30f;
#pragma unroll
    for (int e = 0; e < 8; e++) { l[e] = a[e] + rb[e]; mx = fmaxf(mx, l[e]); }
    float sum = 0.f;
#pragma unroll
    for (int e = 0; e < 8; e++) { l[e] = __expf(l[e] - mx); sum += l[e]; }
    float inv = 1.f / sum;
    int i1 = 0; float p1 = -1.f;
#pragma unroll
    for (int e = 0; e < 8; e++) if (l[e] > p1) { p1 = l[e]; i1 = e; }
    int i2 = -1; float p2 = -1.f;
#pragma unroll
    for (int e = 0; e < 8; e++) if (e != i1 && l[e] > p2) { p2 = l[e]; i2 = e; }
    int pos1 = atomicAdd(&counts[i1], 1);
    int pos2 = atomicAdd(&counts[i2], 1);
    list_token[i1 * T_TOKENS + pos1] = t;
    list_token[i2 * T_TOKENS + pos2] = t;
    epos[2 * t] = (i1 << 16) | pos1;
    epos[2 * t + 1] = (i2 << 16) | pos2;
    escore[2 * t] = p1 * inv;
    escore[2 * t + 1] = p2 * inv;
  }
}

// ---------------- prefix + selected mask ----------------
__global__ __launch_bounds__(64) void finalize_kernel(const int* __restrict__ counts,
                                                      int* __restrict__ offsets,
                                                      float* __restrict__ sel_out) {
  int tid = threadIdx.x;
  if (tid == 0) {
    int o = 0;
    for (int e = 0; e < NE; e++) { offsets[e] = o; o += counts[e]; }
    offsets[NE] = o;
  }
  if (tid < NE) sel_out[tid] = counts[tid] > 0 ? 1.f : 0.f;
}

// ---------------- transpose + convert weights ----------------
// src fp32 [E][R][C] -> dst bf16 [E][C][R]
__global__ __launch_bounds__(256) void transpose_cvt_kernel(
    const float* __restrict__ src, u16* __restrict__ dst, int R, int C) {
  __shared__ float tile[32][33];
  int e = blockIdx.z;
  const float* s = src + (size_t)e * R * C;
  u16* d = dst + (size_t)e * R * C;
  int c0 = blockIdx.x * 32, r0 = blockIdx.y * 32;
  int tx = threadIdx.x, ty = threadIdx.y;
#pragma unroll
  for (int i = 0; i < 4; i++) {
    int r = r0 + ty + i * 8;
    tile[ty + i * 8][tx] = s[(size_t)r * C + c0 + tx];
  }
  __syncthreads();
#pragma unroll
  for (int i = 0; i < 4; i++) {
    int c = c0 + ty + i * 8;
    d[(size_t)c * R + r0 + tx] = f2bf(tile[tx][ty + i * 8]);
  }
}

// ---------------- GEMM1: gathered x @ w1t -> gelu -> H (bf16) ----------------
// grid: (DF/128, 64, NE), block 256
__global__ __launch_bounds__(256) void gemm1_kernel(
    const u16* __restrict__ xb, const u16* __restrict__ w1t,
    const float* __restrict__ b1, const int* __restrict__ counts,
    const int* __restrict__ offsets, const int* __restrict__ list_token,
    u16* __restrict__ H) {
  int e = blockIdx.z;
  int cnt = counts[e];
  int r0 = blockIdx.y * 128;
  if (r0 >= cnt) return;
  int n0 = blockIdx.x * 128;
  int rem = cnt - r0;

  __shared__ __align__(16) u16 As[128 * 32];
  __shared__ __align__(16) u16 Bs[128 * 32];

  int tid = threadIdx.x;
  int ci0 = tid, ci1 = tid + 256;
  int ra0 = ci0 >> 2, ca0 = ci0 & 3;
  int ra1 = ci1 >> 2, ca1 = ci1 & 3;
  const int* lst = list_token + e * T_TOKENS + r0;
  int tok0 = (ra0 < rem) ? lst[ra0] : lst[0];
  int tok1 = (ra1 < rem) ? lst[ra1] : lst[0];
  const u16* gA0 = xb + (size_t)tok0 * DM + ca0 * 8;
  const u16* gA1 = xb + (size_t)tok1 * DM + ca1 * 8;
  const u16* gB0 = w1t + ((size_t)e * DF + n0 + ra0) * DM + ca0 * 8;
  const u16* gB1 = w1t + ((size_t)e * DF + n0 + ra1) * DM + ca1 * 8;

  int lane = tid & 63, wid = tid >> 6;
  int wm = (wid >> 1) * 64, wn = (wid & 1) * 64;
  int ml = lane & 15, quad = lane >> 4;

  v4f acc[4][4];
#pragma unroll
  for (int i = 0; i < 4; i++)
#pragma unroll
    for (int j = 0; j < 4; j++) acc[i][j] = (v4f){0.f, 0.f, 0.f, 0.f};

  for (int k0 = 0; k0 < DM; k0 += 32) {
    *(int4*)&As[ra0 * 32 + ca0 * 8] = *(const int4*)(gA0 + k0);
    *(int4*)&As[ra1 * 32 + ca1 * 8] = *(const int4*)(gA1 + k0);
    *(int4*)&Bs[ra0 * 32 + ca0 * 8] = *(const int4*)(gB0 + k0);
    *(int4*)&Bs[ra1 * 32 + ca1 * 8] = *(const int4*)(gB1 + k0);
    __syncthreads();
    v8s af[4], bf[4];
#pragma unroll
    for (int i = 0; i < 4; i++)
      af[i] = *(const v8s*)&As[(wm + i * 16 + ml) * 32 + quad * 8];
#pragma unroll
    for (int j = 0; j < 4; j++)
      bf[j] = *(const v8s*)&Bs[(wn + j * 16 + ml) * 32 + quad * 8];
#pragma unroll
    for (int i = 0; i < 4; i++)
#pragma unroll
      for (int j = 0; j < 4; j++)
        acc[i][j] = __builtin_amdgcn_mfma_f32_16x16x32_bf16(af[i], bf[j], acc[i][j], 0, 0, 0);
    __syncthreads();
  }

  int slotbase = offsets[e] + r0;
#pragma unroll
  for (int i = 0; i < 4; i++) {
    int rbase = wm + i * 16 + quad * 4;
#pragma unroll
    for (int j = 0; j < 4; j++) {
      int cc = n0 + wn + j * 16 + ml;
      float bias = b1[e * DF + cc];
#pragma unroll
      for (int r = 0; r < 4; r++) {
        int row = rbase + r;
        if (row < rem) {
          float v = acc[i][j][r] + bias;
          float u = 0.7978845608028654f * (v + 0.044715f * v * v * v);
          float h = v / (1.f + __expf(-2.f * u));  // v * sigmoid(2u) == tanh-gelu
          H[(size_t)(slotbase + row) * DF + cc] = f2bf(h);
        }
      }
    }
  }
}

// ---------------- GEMM2: H @ w2t + b2 -> partial (fp32, unscaled) ----------------
// grid: (DM/128, 64, NE), block 256
__global__ __launch_bounds__(256) void gemm2_kernel(
    const u16* __restrict__ H, const u16* __restrict__ w2t,
    const float* __restrict__ b2, const int* __restrict__ counts,
    const int* __restrict__ offsets, float* __restrict__ partial) {
  int e = blockIdx.z;
  int cnt = counts[e];
  int r0 = blockIdx.y * 128;
  if (r0 >= cnt) return;
  int n0 = blockIdx.x * 128;
  int rem = cnt - r0;
  int slotbase = offsets[e] + r0;

  __shared__ __align__(16) u16 As[128 * 32];
  __shared__ __align__(16) u16 Bs[128 * 32];

  int tid = threadIdx.x;
  int ci0 = tid, ci1 = tid + 256;
  int ra0 = ci0 >> 2, ca0 = ci0 & 3;
  int ra1 = ci1 >> 2, ca1 = ci1 & 3;
  int ar0 = (ra0 < rem) ? ra0 : 0;
  int ar1 = (ra1 < rem) ? ra1 : 0;
  const u16* gA0 = H + (size_t)(slotbase + ar0) * DF + ca0 * 8;
  const u16* gA1 = H + (size_t)(slotbase + ar1) * DF + ca1 * 8;
  const u16* gB0 = w2t + ((size_t)e * DM + n0 + ra0) * DF + ca0 * 8;
  const u16* gB1 = w2t + ((size_t)e * DM + n0 + ra1) * DF + ca1 * 8;

  int lane = tid & 63, wid = tid >> 6;
  int wm = (wid >> 1) * 64, wn = (wid & 1) * 64;
  int ml = lane & 15, quad = lane >> 4;

  v4f acc[4][4];
#pragma unroll
  for (int i = 0; i < 4; i++)
#pragma unroll
    for (int j = 0; j < 4; j++) acc[i][j] = (v4f){0.f, 0.f, 0.f, 0.f};

  for (int k0 = 0; k0 < DF; k0 += 32) {
    *(int4*)&As[ra0 * 32 + ca0 * 8] = *(const int4*)(gA0 + k0);
    *(int4*)&As[ra1 * 32 + ca1 * 8] = *(const int4*)(gA1 + k0);
    *(int4*)&Bs[ra0 * 32 + ca0 * 8] = *(const int4*)(gB0 + k0);
    *(int4*)&Bs[ra1 * 32 + ca1 * 8] = *(const int4*)(gB1 + k0);
    __syncthreads();
    v8s af[4], bf[4];
#pragma unroll
    for (int i = 0; i < 4; i++)
      af[i] = *(const v8s*)&As[(wm + i * 16 + ml) * 32 + quad * 8];
#pragma unroll
    for (int j = 0; j < 4; j++)
      bf[j] = *(const v8s*)&Bs[(wn + j * 16 + ml) * 32 + quad * 8];
#pragma unroll
    for (int i = 0; i < 4; i++)
#pragma unroll
      for (int j = 0; j < 4; j++)
        acc[i][j] = __builtin_amdgcn_mfma_f32_16x16x32_bf16(af[i], bf[j], acc[i][j], 0, 0, 0);
    __syncthreads();
  }

#pragma unroll
  for (int i = 0; i < 4; i++) {
    int rbase = wm + i * 16 + quad * 4;
#pragma unroll
    for (int j = 0; j < 4; j++) {
      int cc = n0 + wn + j * 16 + ml;
      float bias = b2[e * DM + cc];
#pragma unroll
      for (int r = 0; r < 4; r++) {
        int row = rbase + r;
        if (row < rem)
          partial[(size_t)(slotbase + row) * DM + cc] = acc[i][j][r] + bias;
      }
    }
  }
}

// ---------------- residual + combine + LayerNorm ----------------
__global__ __launch_bounds__(256) void ln_kernel(
    const float* __restrict__ x, const float* __restrict__ partial,
    const int* __restrict__ offsets, const int* __restrict__ epos,
    const float* __restrict__ escore, const float* __restrict__ gamma,
    const float* __restrict__ beta, float* __restrict__ out) {
  int t = blockIdx.x;
  int tid = threadIdx.x;
  int e0p = epos[2 * t], e1p = epos[2 * t + 1];
  float s0 = escore[2 * t], s1 = escore[2 * t + 1];
  size_t row0 = (size_t)offsets[e0p >> 16] + (e0p & 0xFFFF);
  size_t row1 = (size_t)offsets[e1p >> 16] + (e1p & 0xFFFF);
  float4 xv = ((const float4*)(x + (size_t)t * DM))[tid];
  float4 p0 = ((const float4*)(partial + row0 * DM))[tid];
  float4 p1 = ((const float4*)(partial + row1 * DM))[tid];
  float4 y;
  y.x = xv.x + s0 * p0.x + s1 * p1.x;
  y.y = xv.y + s0 * p0.y + s1 * p1.y;
  y.z = xv.z + s0 * p0.z + s1 * p1.z;
  y.w = xv.w + s0 * p0.w + s1 * p1.w;
  float s = y.x + y.y + y.z + y.w;
  float ss = y.x * y.x + y.y * y.y + y.z * y.z + y.w * y.w;
#pragma unroll
  for (int off = 32; off > 0; off >>= 1) {
    s += __shfl_down(s, off);
    ss += __shfl_down(ss, off);
  }
  __shared__ float red[10];
  int wid = tid >> 6, lane = tid & 63;
  if (lane == 0) { red[wid] = s; red[4 + wid] = ss; }
  __syncthreads();
  if (tid == 0) {
    float S = red[0] + red[1] + red[2] + red[3];
    float SS = red[4] + red[5] + red[6] + red[7];
    float mu = S * (1.f / DM);
    float var = SS * (1.f / DM) - mu * mu;
    red[8] = mu;
    red[9] = rsqrtf(var + 1e-5f);
  }
  __syncthreads();
  float mu = red[8], rs = red[9];
  float4 g = ((const float4*)gamma)[tid];
  float4 b = ((const float4*)beta)[tid];
  float4 z;
  z.x = (y.x - mu) * rs * g.x + b.x;
  z.y = (y.y - mu) * rs * g.y + b.y;
  z.z = (y.z - mu) * rs * g.z + b.z;
  z.w = (y.w - mu) * rs * g.w + b.w;
  ((float4*)(out + (size_t)t * DM))[tid] = z;
}

// ---------------- launch ----------------
extern "C" void kernel_launch(void* const* d_in, const int* in_sizes, int n_in,
                              void* d_out, int out_size, void* d_ws, size_t ws_size,
                              hipStream_t stream) {
  const float* x = (const float*)d_in[0];
  const float* rw = (const float*)d_in[1];
  const float* rb = (const float*)d_in[2];
  const float* w1 = (const float*)d_in[3];
  const float* b1 = (const float*)d_in[4];
  const float* w2 = (const float*)d_in[5];
  const float* b2 = (const float*)d_in[6];
  const float* gamma = (const float*)d_in[7];
  const float* beta = (const float*)d_in[8];
  float* out = (float*)d_out;

  char* ws = (char*)d_ws;
  // layout (bytes):
  //   counts      @ 0        (32)
  //   offsets     @ 256      (36)
  //   list_token  @ 4096     (8*8192*4   = 262144)
  //   epos        @ 266240   (8192*2*4   = 65536)
  //   escore      @ 331776   (8192*2*4   = 65536)
  //   xb   bf16   @ 1048576  (8192*1024*2  = 16777216)
  //   w1t  bf16   @ 17825792 (8*4096*1024*2 = 67108864)
  //   w2t  bf16   @ 84934656 (8*4096*1024*2 = 67108864)
  //   H    bf16   @ 152043520 (16384*4096*2 = 134217728)
  //   partial f32 @ 286261248 (16384*1024*4 = 67108864)  -> total 353370112
  int* counts = (int*)(ws + 0);
  int* offsets = (int*)(ws + 256);
  int* list_token = (int*)(ws + 4096);
  int* epos = (int*)(ws + 266240);
  float* escore = (float*)(ws + 331776);
  u16* xb = (u16*)(ws + 1048576);
  u16* w1t = (u16*)(ws + 17825792);
  u16* w2t = (u16*)(ws + 84934656);
  u16* H = (u16*)(ws + 152043520);
  float* partial = (float*)(ws + 286261248);

  hipMemsetAsync(counts, 0, NE * sizeof(int), stream);

  cvt_x_kernel<<<dim3(4096), dim3(256), 0, stream>>>(x, xb);
  router_kernel<<<dim3(T_TOKENS), dim3(64), 0, stream>>>(x, rw, rb, counts,
                                                         list_token, epos, escore);
  finalize_kernel<<<dim3(1), dim3(64), 0, stream>>>(
      counts, offsets, out + (size_t)T_TOKENS * DM);
  // w1 [E][1024][4096] -> w1t [E][4096][1024]
  transpose_cvt_kernel<<<dim3(128, 32, NE), dim3(32, 8), 0, stream>>>(w1, w1t, DM, DF);
  // w2 [E][4096][1024] -> w2t [E][1024][4096]
  transpose_cvt_kernel<<<dim3(32, 128, NE), dim3(32, 8), 0, stream>>>(w2, w2t, DF, DM);

  gemm1_kernel<<<dim3(DF / 128, 64, NE), dim3(256), 0, stream>>>(
      xb, w1t, b1, counts, offsets, list_token, H);
  gemm2_kernel<<<dim3(DM / 128, 64, NE), dim3(256), 0, stream>>>(
      H, w2t, b2, counts, offsets, partial);
  ln_kernel<<<dim3(T_TOKENS), dim3(256), 0, stream>>>(x, partial, offsets, epos,
                                                      escore, gamma, beta, out);
}

// Round 2
// 1034.129 us; speedup vs baseline: 1.0528x; 1.0528x over previous
//
#include <hip/hip_runtime.h>

// MoE block: router(top-2 of 8) -> per-expert [M,1024]@[1024,4096] GELU
// -> [M,4096]@[4096,1024] -> scale/combine -> residual + LayerNorm.
// bf16 MFMA (16x16x32), fp32 router/accum/epilogue.
// R2: m97-style global_load_lds width-16 staging in both GEMMs;
//     u32-wide transpose stores.

#define T_TOKENS 8192
#define DM 1024
#define DF 4096
#define NE 8

typedef unsigned short u16;
typedef short v8s __attribute__((ext_vector_type(8)));
typedef float v4f __attribute__((ext_vector_type(4)));

__device__ __forceinline__ u16 f2bf(float f) {
  unsigned u = __float_as_uint(f);
  u += 0x7FFFu + ((u >> 16) & 1u);
  return (u16)(u >> 16);
}

// async global -> LDS, 16B per lane; lds must be wave-uniform base,
// HW writes at base + lane*16.
__device__ __forceinline__ void load16_lds(const u16* g, u16* lds) {
  __builtin_amdgcn_global_load_lds(
      (const __attribute__((address_space(1))) unsigned int*)g,
      (__attribute__((address_space(3))) unsigned int*)lds, 16, 0, 0);
}

// ---------------- x -> bf16 ----------------
__global__ __launch_bounds__(256) void cvt_x_kernel(const float* __restrict__ x,
                                                    u16* __restrict__ xb) {
  size_t i = ((size_t)blockIdx.x * 256 + threadIdx.x) * 8;
  float4 v0 = *(const float4*)(x + i);
  float4 v1 = *(const float4*)(x + i + 4);
  int4 o;
  o.x = (int)f2bf(v0.x) | ((int)f2bf(v0.y) << 16);
  o.y = (int)f2bf(v0.z) | ((int)f2bf(v0.w) << 16);
  o.z = (int)f2bf(v1.x) | ((int)f2bf(v1.y) << 16);
  o.w = (int)f2bf(v1.z) | ((int)f2bf(v1.w) << 16);
  *(int4*)(xb + i) = o;
}

// ---------------- router ----------------
__global__ __launch_bounds__(64) void router_kernel(
    const float* __restrict__ x, const float* __restrict__ rw,
    const float* __restrict__ rb, int* __restrict__ counts,
    int* __restrict__ list_token, int* __restrict__ epos,
    float* __restrict__ escore) {
  int t = blockIdx.x;
  int lane = threadIdx.x;
  const float* xr = x + (size_t)t * DM;
  float a[8] = {0.f, 0.f, 0.f, 0.f, 0.f, 0.f, 0.f, 0.f};
  for (int j = lane; j < DM; j += 64) {
    float xv = xr[j];
    const float4* r4 = (const float4*)(rw + (size_t)j * 8);
    float4 w0 = r4[0], w1 = r4[1];
    a[0] += xv * w0.x; a[1] += xv * w0.y; a[2] += xv * w0.z; a[3] += xv * w0.w;
    a[4] += xv * w1.x; a[5] += xv * w1.y; a[6] += xv * w1.z; a[7] += xv * w1.w;
  }
#pragma unroll
  for (int e = 0; e < 8; e++)
#pragma unroll
    for (int off = 32; off > 0; off >>= 1) a[e] += __shfl_down(a[e], off);
  if (lane == 0) {
    float l[8];
    float mx = -1e30f;
#pragma unroll
    for (int e = 0; e < 8; e++) { l[e] = a[e] + rb[e]; mx = fmaxf(mx, l[e]); }
    float sum = 0.f;
#pragma unroll
    for (int e = 0; e < 8; e++) { l[e] = __expf(l[e] - mx); sum += l[e]; }
    float inv = 1.f / sum;
    int i1 = 0; float p1 = -1.f;
#pragma unroll
    for (int e = 0; e < 8; e++) if (l[e] > p1) { p1 = l[e]; i1 = e; }
    int i2 = -1; float p2 = -1.f;
#pragma unroll
    for (int e = 0; e < 8; e++) if (e != i1 && l[e] > p2) { p2 = l[e]; i2 = e; }
    int pos1 = atomicAdd(&counts[i1], 1);
    int pos2 = atomicAdd(&counts[i2], 1);
    list_token[i1 * T_TOKENS + pos1] = t;
    list_token[i2 * T_TOKENS + pos2] = t;
    epos[2 * t] = (i1 << 16) | pos1;
    epos[2 * t + 1] = (i2 << 16) | pos2;
    escore[2 * t] = p1 * inv;
    escore[2 * t + 1] = p2 * inv;
  }
}

// ---------------- prefix + selected mask ----------------
__global__ __launch_bounds__(64) void finalize_kernel(const int* __restrict__ counts,
                                                      int* __restrict__ offsets,
                                                      float* __restrict__ sel_out) {
  int tid = threadIdx.x;
  if (tid == 0) {
    int o = 0;
    for (int e = 0; e < NE; e++) { offsets[e] = o; o += counts[e]; }
    offsets[NE] = o;
  }
  if (tid < NE) sel_out[tid] = counts[tid] > 0 ? 1.f : 0.f;
}

// ---------------- transpose + convert weights ----------------
// src fp32 [E][R][C] -> dst bf16 [E][C][R]; 64-row x 32-col tiles,
// u32 (2x bf16) stores on the transposed side.
__global__ __launch_bounds__(256) void transpose_cvt_kernel(
    const float* __restrict__ src, u16* __restrict__ dst, int R, int C) {
  __shared__ float tile[64][33];
  int e = blockIdx.z;
  const float* s = src + (size_t)e * R * C;
  u16* d = dst + (size_t)e * R * C;
  int c0 = blockIdx.x * 32, r0 = blockIdx.y * 64;
  int tx = threadIdx.x, ty = threadIdx.y;  // (32, 8)
#pragma unroll
  for (int i = 0; i < 8; i++) {
    int r = r0 + ty + i * 8;
    tile[ty + i * 8][tx] = s[(size_t)r * C + c0 + tx];
  }
  __syncthreads();
#pragma unroll
  for (int i = 0; i < 4; i++) {
    int c = c0 + ty + i * 8;
    unsigned lo = f2bf(tile[2 * tx][ty + i * 8]);
    unsigned hi = f2bf(tile[2 * tx + 1][ty + i * 8]);
    *(unsigned*)&d[(size_t)c * R + r0 + 2 * tx] = lo | (hi << 16);
  }
}

// ---------------- GEMM1: gathered x @ w1t -> gelu -> H (bf16) ----------------
// grid: (DF/128, 64, NE), block 256
__global__ __launch_bounds__(256) void gemm1_kernel(
    const u16* __restrict__ xb, const u16* __restrict__ w1t,
    const float* __restrict__ b1, const int* __restrict__ counts,
    const int* __restrict__ offsets, const int* __restrict__ list_token,
    u16* __restrict__ H) {
  int e = blockIdx.z;
  int cnt = counts[e];
  int r0 = blockIdx.y * 128;
  if (r0 >= cnt) return;
  int n0 = blockIdx.x * 128;
  int rem = cnt - r0;

  __shared__ __align__(16) u16 As[128 * 32];
  __shared__ __align__(16) u16 Bs[128 * 32];

  int tid = threadIdx.x;
  int ra0 = tid >> 2, ca0 = tid & 3;
  int ra1 = ra0 + 64, ca1 = ca0;
  const int* lst = list_token + e * T_TOKENS + r0;
  int tok0 = (ra0 < rem) ? lst[ra0] : lst[0];
  int tok1 = (ra1 < rem) ? lst[ra1] : lst[0];
  const u16* gA0 = xb + (size_t)tok0 * DM + ca0 * 8;
  const u16* gA1 = xb + (size_t)tok1 * DM + ca1 * 8;
  const u16* gB0 = w1t + ((size_t)e * DF + n0 + ra0) * DM + ca0 * 8;
  const u16* gB1 = w1t + ((size_t)e * DF + n0 + ra1) * DM + ca1 * 8;

  int lane = tid & 63, wv = tid >> 6;
  // wave-uniform LDS bases: thread tid covers LDS bytes [tid*16, tid*16+16)
  u16* ldsA0 = As + wv * 512;
  u16* ldsA1 = As + 2048 + wv * 512;
  u16* ldsB0 = Bs + wv * 512;
  u16* ldsB1 = Bs + 2048 + wv * 512;

  int wm = (wv >> 1) * 64, wn = (wv & 1) * 64;
  int ml = lane & 15, quad = lane >> 4;

  v4f acc[4][4];
#pragma unroll
  for (int i = 0; i < 4; i++)
#pragma unroll
    for (int j = 0; j < 4; j++) acc[i][j] = (v4f){0.f, 0.f, 0.f, 0.f};

  for (int k0 = 0; k0 < DM; k0 += 32) {
    load16_lds(gA0 + k0, ldsA0);
    load16_lds(gA1 + k0, ldsA1);
    load16_lds(gB0 + k0, ldsB0);
    load16_lds(gB1 + k0, ldsB1);
    __syncthreads();
    v8s af[4], bf[4];
#pragma unroll
    for (int i = 0; i < 4; i++)
      af[i] = *(const v8s*)&As[(wm + i * 16 + ml) * 32 + quad * 8];
#pragma unroll
    for (int j = 0; j < 4; j++)
      bf[j] = *(const v8s*)&Bs[(wn + j * 16 + ml) * 32 + quad * 8];
#pragma unroll
    for (int i = 0; i < 4; i++)
#pragma unroll
      for (int j = 0; j < 4; j++)
        acc[i][j] = __builtin_amdgcn_mfma_f32_16x16x32_bf16(af[i], bf[j], acc[i][j], 0, 0, 0);
    __syncthreads();
  }

  int slotbase = offsets[e] + r0;
#pragma unroll
  for (int i = 0; i < 4; i++) {
    int rbase = wm + i * 16 + quad * 4;
#pragma unroll
    for (int j = 0; j < 4; j++) {
      int cc = n0 + wn + j * 16 + ml;
      float bias = b1[e * DF + cc];
#pragma unroll
      for (int r = 0; r < 4; r++) {
        int row = rbase + r;
        if (row < rem) {
          float v = acc[i][j][r] + bias;
          float u = 0.7978845608028654f * (v + 0.044715f * v * v * v);
          float h = v / (1.f + __expf(-2.f * u));  // v * sigmoid(2u) == tanh-gelu
          H[(size_t)(slotbase + row) * DF + cc] = f2bf(h);
        }
      }
    }
  }
}

// ---------------- GEMM2: H @ w2t + b2 -> partial (fp32, unscaled) ----------------
// grid: (DM/128, 64, NE), block 256
__global__ __launch_bounds__(256) void gemm2_kernel(
    const u16* __restrict__ H, const u16* __restrict__ w2t,
    const float* __restrict__ b2, const int* __restrict__ counts,
    const int* __restrict__ offsets, float* __restrict__ partial) {
  int e = blockIdx.z;
  int cnt = counts[e];
  int r0 = blockIdx.y * 128;
  if (r0 >= cnt) return;
  int n0 = blockIdx.x * 128;
  int rem = cnt - r0;
  int slotbase = offsets[e] + r0;

  __shared__ __align__(16) u16 As[128 * 32];
  __shared__ __align__(16) u16 Bs[128 * 32];

  int tid = threadIdx.x;
  int ra0 = tid >> 2, ca0 = tid & 3;
  int ra1 = ra0 + 64, ca1 = ca0;
  int ar0 = (ra0 < rem) ? ra0 : 0;
  int ar1 = (ra1 < rem) ? ra1 : 0;
  const u16* gA0 = H + (size_t)(slotbase + ar0) * DF + ca0 * 8;
  const u16* gA1 = H + (size_t)(slotbase + ar1) * DF + ca1 * 8;
  const u16* gB0 = w2t + ((size_t)e * DM + n0 + ra0) * DF + ca0 * 8;
  const u16* gB1 = w2t + ((size_t)e * DM + n0 + ra1) * DF + ca1 * 8;

  int lane = tid & 63, wv = tid >> 6;
  u16* ldsA0 = As + wv * 512;
  u16* ldsA1 = As + 2048 + wv * 512;
  u16* ldsB0 = Bs + wv * 512;
  u16* ldsB1 = Bs + 2048 + wv * 512;

  int wm = (wv >> 1) * 64, wn = (wv & 1) * 64;
  int ml = lane & 15, quad = lane >> 4;

  v4f acc[4][4];
#pragma unroll
  for (int i = 0; i < 4; i++)
#pragma unroll
    for (int j = 0; j < 4; j++) acc[i][j] = (v4f){0.f, 0.f, 0.f, 0.f};

  for (int k0 = 0; k0 < DF; k0 += 32) {
    load16_lds(gA0 + k0, ldsA0);
    load16_lds(gA1 + k0, ldsA1);
    load16_lds(gB0 + k0, ldsB0);
    load16_lds(gB1 + k0, ldsB1);
    __syncthreads();
    v8s af[4], bf[4];
#pragma unroll
    for (int i = 0; i < 4; i++)
      af[i] = *(const v8s*)&As[(wm + i * 16 + ml) * 32 + quad * 8];
#pragma unroll
    for (int j = 0; j < 4; j++)
      bf[j] = *(const v8s*)&Bs[(wn + j * 16 + ml) * 32 + quad * 8];
#pragma unroll
    for (int i = 0; i < 4; i++)
#pragma unroll
      for (int j = 0; j < 4; j++)
        acc[i][j] = __builtin_amdgcn_mfma_f32_16x16x32_bf16(af[i], bf[j], acc[i][j], 0, 0, 0);
    __syncthreads();
  }

#pragma unroll
  for (int i = 0; i < 4; i++) {
    int rbase = wm + i * 16 + quad * 4;
#pragma unroll
    for (int j = 0; j < 4; j++) {
      int cc = n0 + wn + j * 16 + ml;
      float bias = b2[e * DM + cc];
#pragma unroll
      for (int r = 0; r < 4; r++) {
        int row = rbase + r;
        if (row < rem)
          partial[(size_t)(slotbase + row) * DM + cc] = acc[i][j][r] + bias;
      }
    }
  }
}

// ---------------- residual + combine + LayerNorm ----------------
__global__ __launch_bounds__(256) void ln_kernel(
    const float* __restrict__ x, const float* __restrict__ partial,
    const int* __restrict__ offsets, const int* __restrict__ epos,
    const float* __restrict__ escore, const float* __restrict__ gamma,
    const float* __restrict__ beta, float* __restrict__ out) {
  int t = blockIdx.x;
  int tid = threadIdx.x;
  int e0p = epos[2 * t], e1p = epos[2 * t + 1];
  float s0 = escore[2 * t], s1 = escore[2 * t + 1];
  size_t row0 = (size_t)offsets[e0p >> 16] + (e0p & 0xFFFF);
  size_t row1 = (size_t)offsets[e1p >> 16] + (e1p & 0xFFFF);
  float4 xv = ((const float4*)(x + (size_t)t * DM))[tid];
  float4 p0 = ((const float4*)(partial + row0 * DM))[tid];
  float4 p1 = ((const float4*)(partial + row1 * DM))[tid];
  float4 y;
  y.x = xv.x + s0 * p0.x + s1 * p1.x;
  y.y = xv.y + s0 * p0.y + s1 * p1.y;
  y.z = xv.z + s0 * p0.z + s1 * p1.z;
  y.w = xv.w + s0 * p0.w + s1 * p1.w;
  float s = y.x + y.y + y.z + y.w;
  float ss = y.x * y.x + y.y * y.y + y.z * y.z + y.w * y.w;
#pragma unroll
  for (int off = 32; off > 0; off >>= 1) {
    s += __shfl_down(s, off);
    ss += __shfl_down(ss, off);
  }
  __shared__ float red[10];
  int wid = tid >> 6, lane = tid & 63;
  if (lane == 0) { red[wid] = s; red[4 + wid] = ss; }
  __syncthreads();
  if (tid == 0) {
    float S = red[0] + red[1] + red[2] + red[3];
    float SS = red[4] + red[5] + red[6] + red[7];
    float mu = S * (1.f / DM);
    float var = SS * (1.f / DM) - mu * mu;
    red[8] = mu;
    red[9] = rsqrtf(var + 1e-5f);
  }
  __syncthreads();
  float mu = red[8], rs = red[9];
  float4 g = ((const float4*)gamma)[tid];
  float4 b = ((const float4*)beta)[tid];
  float4 z;
  z.x = (y.x - mu) * rs * g.x + b.x;
  z.y = (y.y - mu) * rs * g.y + b.y;
  z.z = (y.z - mu) * rs * g.z + b.z;
  z.w = (y.w - mu) * rs * g.w + b.w;
  ((float4*)(out + (size_t)t * DM))[tid] = z;
}

// ---------------- launch ----------------
extern "C" void kernel_launch(void* const* d_in, const int* in_sizes, int n_in,
                              void* d_out, int out_size, void* d_ws, size_t ws_size,
                              hipStream_t stream) {
  const float* x = (const float*)d_in[0];
  const float* rw = (const float*)d_in[1];
  const float* rb = (const float*)d_in[2];
  const float* w1 = (const float*)d_in[3];
  const float* b1 = (const float*)d_in[4];
  const float* w2 = (const float*)d_in[5];
  const float* b2 = (const float*)d_in[6];
  const float* gamma = (const float*)d_in[7];
  const float* beta = (const float*)d_in[8];
  float* out = (float*)d_out;

  char* ws = (char*)d_ws;
  int* counts = (int*)(ws + 0);
  int* offsets = (int*)(ws + 256);
  int* list_token = (int*)(ws + 4096);
  int* epos = (int*)(ws + 266240);
  float* escore = (float*)(ws + 331776);
  u16* xb = (u16*)(ws + 1048576);
  u16* w1t = (u16*)(ws + 17825792);
  u16* w2t = (u16*)(ws + 84934656);
  u16* H = (u16*)(ws + 152043520);
  float* partial = (float*)(ws + 286261248);

  hipMemsetAsync(counts, 0, NE * sizeof(int), stream);

  cvt_x_kernel<<<dim3(4096), dim3(256), 0, stream>>>(x, xb);
  router_kernel<<<dim3(T_TOKENS), dim3(64), 0, stream>>>(x, rw, rb, counts,
                                                         list_token, epos, escore);
  finalize_kernel<<<dim3(1), dim3(64), 0, stream>>>(
      counts, offsets, out + (size_t)T_TOKENS * DM);
  // w1 [E][1024][4096] -> w1t [E][4096][1024]
  transpose_cvt_kernel<<<dim3(128, 16, NE), dim3(32, 8), 0, stream>>>(w1, w1t, DM, DF);
  // w2 [E][4096][1024] -> w2t [E][1024][4096]
  transpose_cvt_kernel<<<dim3(32, 64, NE), dim3(32, 8), 0, stream>>>(w2, w2t, DF, DM);

  gemm1_kernel<<<dim3(DF / 128, 64, NE), dim3(256), 0, stream>>>(
      xb, w1t, b1, counts, offsets, list_token, H);
  gemm2_kernel<<<dim3(DM / 128, 64, NE), dim3(256), 0, stream>>>(
      H, w2t, b2, counts, offsets, partial);
  ln_kernel<<<dim3(T_TOKENS), dim3(256), 0, stream>>>(x, partial, offsets, epos,
                                                      escore, gamma, beta, out);
}